// Round 2
// baseline (18.021 us; speedup 1.0000x reference)
//
#include <hip/hip_runtime.h>
#include <math.h>

#define RW 256          // render width  (u axis, output axis 0)
#define RH 256          // render height (v axis, output axis 1)
#define VN 256          // volume resolution per axis
#define TFN 128
#define MAXS 256
#define BATCH 8

__global__ __launch_bounds__(256, 1) void raycast_kernel(
    const float* __restrict__ vol,   // (256,256,256) row-major: x*65536+y*256+z
    const float4* __restrict__ tf,   // (128,4)
    const float* __restrict__ lf3,   // (3,)
    float* __restrict__ out)         // (256,256,4)
{
    __shared__ float4 tf_s[TFN];
    if (threadIdx.x < TFN) tf_s[threadIdx.x] = tf[threadIdx.x];
    __syncthreads();

    const int tx = threadIdx.x & 15;
    const int ty = threadIdx.x >> 4;
    const int px = blockIdx.x * 16 + tx;   // u / output axis 0
    const int py = blockIdx.y * 16 + ty;   // v / output axis 1

    const float lfx = lf3[0], lfy = lf3[1], lfz = lf3[2];

    // view_dir = normalize(-look_from)
    float inv = rsqrtf(lfx * lfx + lfy * lfy + lfz * lfz);
    const float vdx = -lfx * inv, vdy = -lfy * inv, vdz = -lfz * inv;

    // right = normalize(cross(view_dir, (0,1,0))) = normalize((-vdz, 0, vdx))
    float rx = -vdz, rz = vdx;
    inv = rsqrtf(rx * rx + rz * rz);
    rx *= inv; rz *= inv;

    // up = normalize(cross(right, view_dir));  right.y == 0
    float ux = -rz * vdy;
    float uy = rz * vdx - rx * vdz;
    float uz = rx * vdy;
    inv = rsqrtf(ux * ux + uy * uy + uz * uz);
    ux *= inv; uy *= inv; uz *= inv;

    const float NEAR = 0.1f;
    const float near_h = 2.0f * tanf(0.5235987755982988f) * NEAR; // fov=30deg
    const float near_w = near_h;  // aspect = 1

    const float u = ((float)px + 0.5f) / (float)RW - 0.5f;
    const float v = ((float)py + 0.5f) / (float)RH - 0.5f;

    float rdx = NEAR * vdx + u * near_w * rx + v * near_h * ux;
    float rdy = NEAR * vdy              + v * near_h * uy;   // right.y == 0
    float rdz = NEAR * vdz + u * near_w * rz + v * near_h * uz;
    inv = rsqrtf(rdx * rdx + rdy * rdy + rdz * rdz);
    rdx *= inv; rdy *= inv; rdz *= inv;

    // slab test against [-1,1]^3
    const float sdx = (fabsf(rdx) < 1e-9f) ? 1e-9f : rdx;
    const float sdy = (fabsf(rdy) < 1e-9f) ? 1e-9f : rdy;
    const float sdz = (fabsf(rdz) < 1e-9f) ? 1e-9f : rdz;
    const float dfx = 1.0f / sdx, dfy = 1.0f / sdy, dfz = 1.0f / sdz;
    const float t1x = (-1.0f - lfx) * dfx, t2x = (1.0f - lfx) * dfx;
    const float t1y = (-1.0f - lfy) * dfy, t2y = (1.0f - lfy) * dfy;
    const float t1z = (-1.0f - lfz) * dfz, t2z = (1.0f - lfz) * dfz;
    const float tmin = fmaxf(fminf(t1x, t2x), fmaxf(fminf(t1y, t2y), fminf(t1z, t2z)));
    const float tmax = fminf(fmaxf(t1x, t2x), fminf(fmaxf(t1y, t2y), fmaxf(t1z, t2z)));
    const bool hit = (tmax >= 0.0f) && (tmin <= tmax);
    const float entry = fmaxf(tmin, 0.0f);
    const float ray_len = fmaxf(tmax - entry, 0.0f);

    // n_samples = clip(ceil(VOL_DIAG * ray_len / 2), 1, 256); VOL_DIAG = 256*sqrt(3)
    const float nsf = fminf(fmaxf(ceilf(443.4050067376326f * ray_len / 2.0f), 1.0f),
                            (float)MAXS);
    const int n = (int)nsf;
    const float dt = ray_len / nsf;

    float acc_r = 0.0f, acc_g = 0.0f, acc_b = 0.0f, acc_a = 0.0f;

    if (hit) {
        const float scale = 255.0f - 1e-4f;  // (shp - 1 - 1e-4)
        for (int k0 = 0; k0 < n; k0 += BATCH) {
            if (acc_a >= 0.99f) break;

            // ---- phase 1: issue all gathers for BATCH samples ----
            float cs[BATCH][8];
            float fxs[BATCH], fys[BATCH], fzs[BATCH];
            #pragma unroll
            for (int j = 0; j < BATCH; ++j) {
                const float t = entry + ((float)(k0 + j) + 0.5f) * dt;
                const float posx = lfx + rdx * t;
                const float posy = lfy + rdy * t;
                const float posz = lfz + rdz * t;

                const float pxf = fminf(fmaxf(0.5f * posx + 0.5f, 0.0f), 1.0f) * scale;
                const float pyf = fminf(fmaxf(0.5f * posy + 0.5f, 0.0f), 1.0f) * scale;
                const float pzf = fminf(fmaxf(0.5f * posz + 0.5f, 0.0f), 1.0f) * scale;
                const float flx = floorf(pxf), fly = floorf(pyf), flz = floorf(pzf);
                fxs[j] = pxf - flx; fys[j] = pyf - fly; fzs[j] = pzf - flz;
                const int x0 = (int)flx, y0 = (int)fly, z0 = (int)flz;
                const int x1 = min(x0 + 1, VN - 1);
                const int y1 = min(y0 + 1, VN - 1);
                const int z1 = min(z0 + 1, VN - 1);

                const int bx0 = x0 << 16, bx1 = x1 << 16;      // *65536
                const int by0 = y0 << 8,  by1 = y1 << 8;       // *256
                cs[j][0] = vol[bx0 + by0 + z0];
                cs[j][1] = vol[bx1 + by0 + z0];
                cs[j][2] = vol[bx0 + by1 + z0];
                cs[j][3] = vol[bx1 + by1 + z0];
                cs[j][4] = vol[bx0 + by0 + z1];
                cs[j][5] = vol[bx1 + by0 + z1];
                cs[j][6] = vol[bx0 + by1 + z1];
                cs[j][7] = vol[bx1 + by1 + z1];
            }

            // ---- phase 2: consume ----
            #pragma unroll
            for (int j = 0; j < BATCH; ++j) {
                const float fx = fxs[j], fy = fys[j], fz = fzs[j];
                const float c00 = cs[j][0] * (1.0f - fx) + cs[j][1] * fx;
                const float c10 = cs[j][2] * (1.0f - fx) + cs[j][3] * fx;
                const float c01 = cs[j][4] * (1.0f - fx) + cs[j][5] * fx;
                const float c11 = cs[j][6] * (1.0f - fx) + cs[j][7] * fx;
                const float c0 = c00 * (1.0f - fy) + c10 * fy;
                const float c1 = c01 * (1.0f - fy) + c11 * fy;
                const float intensity = c0 * (1.0f - fz) + c1 * fz;

                const float ti = fminf(fmaxf(intensity, 0.0f), 1.0f) * (float)(TFN - 1);
                const float tl = floorf(ti);
                const float tfr = ti - tl;
                const int i0 = (int)tl;
                const int i1 = min(i0 + 1, TFN - 1);
                const float om = 1.0f - tfr;
                const float4 tlo = tf_s[i0];
                const float4 thi = tf_s[i1];
                const float r = tlo.x * om + thi.x * tfr;
                const float g = tlo.y * om + thi.y * tfr;
                const float b = tlo.z * om + thi.z * tfr;
                const float a = tlo.w * om + thi.w * tfr;

                // SAMPLING_RATE == 1 -> pow(x, 1.0) == x
                const bool valid = ((k0 + j) < n) && (acc_a < 0.99f);
                const float alpha = valid ? (1.0f - fmaxf(1.0f - a, 1e-7f)) : 0.0f;
                const float w = (1.0f - acc_a) * alpha;
                acc_r += w * r;
                acc_g += w * g;
                acc_b += w * b;
                acc_a += w;
            }
        }
    }

    const int o = (px * RH + py) * 4;
    out[o + 0] = acc_r;
    out[o + 1] = acc_g;
    out[o + 2] = acc_b;
    out[o + 3] = acc_a;
}

extern "C" void kernel_launch(void* const* d_in, const int* in_sizes, int n_in,
                              void* d_out, int out_size, void* d_ws, size_t ws_size,
                              hipStream_t stream) {
    const float* vol = (const float*)d_in[0];
    const float4* tf = (const float4*)d_in[1];
    const float* lf  = (const float*)d_in[2];
    float* out = (float*)d_out;

    dim3 grid(RW / 16, RH / 16);   // 16x16 pixel tiles, 256 threads each
    raycast_kernel<<<grid, 256, 0, stream>>>(vol, tf, lf, out);
}

// Round 3
// 13.004 us; speedup vs baseline: 1.3858x; 1.3858x over previous
//
#include <hip/hip_runtime.h>
#include <math.h>

#define RW 256          // render width  (u axis, output axis 0)
#define RH 256          // render height (v axis, output axis 1)
#define VN 256          // volume resolution per axis
#define TFN 128
#define MAXS 256

__global__ __launch_bounds__(256, 1) void raycast_kernel(
    const float* __restrict__ vol,   // (256,256,256) row-major: x*65536+y*256+z
    const float4* __restrict__ tf,   // (128,4)
    const float* __restrict__ lf3,   // (3,)
    float* __restrict__ out)         // (256,256,4)
{
    __shared__ float4 tf_s[TFN];
    if (threadIdx.x < TFN) tf_s[threadIdx.x] = tf[threadIdx.x];
    __syncthreads();

    // 8x8 pixel tile per wave (tighter volume footprint than 16x4):
    // block = 16x16 pixels, 4 waves; wave w takes quadrant (w&1, w>>1).
    const int lane = threadIdx.x & 63;
    const int wid  = threadIdx.x >> 6;
    const int tx = (wid & 1) * 8 + (lane & 7);
    const int ty = (wid >> 1) * 8 + (lane >> 3);
    const int px = blockIdx.x * 16 + tx;   // u / output axis 0
    const int py = blockIdx.y * 16 + ty;   // v / output axis 1

    const float lfx = lf3[0], lfy = lf3[1], lfz = lf3[2];

    // view_dir = normalize(-look_from)
    float inv = rsqrtf(lfx * lfx + lfy * lfy + lfz * lfz);
    const float vdx = -lfx * inv, vdy = -lfy * inv, vdz = -lfz * inv;

    // right = normalize(cross(view_dir, (0,1,0))) = normalize((-vdz, 0, vdx))
    float rx = -vdz, rz = vdx;
    inv = rsqrtf(rx * rx + rz * rz);
    rx *= inv; rz *= inv;

    // up = normalize(cross(right, view_dir));  right.y == 0
    float ux = -rz * vdy;
    float uy = rz * vdx - rx * vdz;
    float uz = rx * vdy;
    inv = rsqrtf(ux * ux + uy * uy + uz * uz);
    ux *= inv; uy *= inv; uz *= inv;

    const float NEAR = 0.1f;
    const float near_h = 2.0f * tanf(0.5235987755982988f) * NEAR; // fov=30deg
    const float near_w = near_h;  // aspect = 1

    const float u = ((float)px + 0.5f) / (float)RW - 0.5f;
    const float v = ((float)py + 0.5f) / (float)RH - 0.5f;

    float rdx = NEAR * vdx + u * near_w * rx + v * near_h * ux;
    float rdy = NEAR * vdy              + v * near_h * uy;   // right.y == 0
    float rdz = NEAR * vdz + u * near_w * rz + v * near_h * uz;
    inv = rsqrtf(rdx * rdx + rdy * rdy + rdz * rdz);
    rdx *= inv; rdy *= inv; rdz *= inv;

    // slab test against [-1,1]^3
    const float sdx = (fabsf(rdx) < 1e-9f) ? 1e-9f : rdx;
    const float sdy = (fabsf(rdy) < 1e-9f) ? 1e-9f : rdy;
    const float sdz = (fabsf(rdz) < 1e-9f) ? 1e-9f : rdz;
    const float dfx = 1.0f / sdx, dfy = 1.0f / sdy, dfz = 1.0f / sdz;
    const float t1x = (-1.0f - lfx) * dfx, t2x = (1.0f - lfx) * dfx;
    const float t1y = (-1.0f - lfy) * dfy, t2y = (1.0f - lfy) * dfy;
    const float t1z = (-1.0f - lfz) * dfz, t2z = (1.0f - lfz) * dfz;
    const float tmin = fmaxf(fminf(t1x, t2x), fmaxf(fminf(t1y, t2y), fminf(t1z, t2z)));
    const float tmax = fminf(fmaxf(t1x, t2x), fminf(fmaxf(t1y, t2y), fmaxf(t1z, t2z)));
    const bool hit = (tmax >= 0.0f) && (tmin <= tmax);
    const float entry = fmaxf(tmin, 0.0f);
    const float ray_len = fmaxf(tmax - entry, 0.0f);

    // n_samples = clip(ceil(VOL_DIAG * ray_len / 2), 1, 256); VOL_DIAG = 256*sqrt(3)
    const float nsf = fminf(fmaxf(ceilf(443.4050067376326f * ray_len / 2.0f), 1.0f),
                            (float)MAXS);
    const int n = (int)nsf;
    const float dt = ray_len / nsf;

    float acc_r = 0.0f, acc_g = 0.0f, acc_b = 0.0f, acc_a = 0.0f;

    if (hit) {
        const float scale = 255.0f - 1e-4f;  // (shp - 1 - 1e-4); => p < 255, hi never clamps
        // z-pairs are always contiguous -> 4x float2 gathers per sample
        auto issue = [&](int k, float2& A, float2& B, float2& C, float2& D,
                         float& fx, float& fy, float& fz) {
            const float t = entry + ((float)k + 0.5f) * dt;
            const float posx = lfx + rdx * t;
            const float posy = lfy + rdy * t;
            const float posz = lfz + rdz * t;
            const float pxf = fminf(fmaxf(0.5f * posx + 0.5f, 0.0f), 1.0f) * scale;
            const float pyf = fminf(fmaxf(0.5f * posy + 0.5f, 0.0f), 1.0f) * scale;
            const float pzf = fminf(fmaxf(0.5f * posz + 0.5f, 0.0f), 1.0f) * scale;
            const float flx = floorf(pxf), fly = floorf(pyf), flz = floorf(pzf);
            fx = pxf - flx; fy = pyf - fly; fz = pzf - flz;
            const int x0 = (int)flx, y0 = (int)fly, z0 = (int)flz;
            const float* p = vol + ((x0 << 16) + (y0 << 8) + z0);
            A = *(const float2*)p;                   // c000, c001
            B = *(const float2*)(p + 65536);         // c100, c101
            C = *(const float2*)(p + 256);           // c010, c011
            D = *(const float2*)(p + 65536 + 256);   // c110, c111
        };

        float2 A, B, C, D;
        float fx, fy, fz;
        issue(0, A, B, C, D, fx, fy, fz);

        for (int k = 0;;) {
            // prefetch k+1 while sample k's values are consumed below
            float2 A2, B2, C2, D2;
            float fx2, fy2, fz2;
            const bool more = (k + 1) < n;
            if (more) issue(k + 1, A2, B2, C2, D2, fx2, fy2, fz2);

            // consume sample k
            const float c00 = A.x * (1.0f - fx) + B.x * fx;
            const float c10 = C.x * (1.0f - fx) + D.x * fx;
            const float c01 = A.y * (1.0f - fx) + B.y * fx;
            const float c11 = C.y * (1.0f - fx) + D.y * fx;
            const float c0 = c00 * (1.0f - fy) + c10 * fy;
            const float c1 = c01 * (1.0f - fy) + c11 * fy;
            const float intensity = c0 * (1.0f - fz) + c1 * fz;

            const float ti = fminf(fmaxf(intensity, 0.0f), 1.0f) * (float)(TFN - 1);
            const float tl = floorf(ti);
            const float tfr = ti - tl;
            const int i0 = (int)tl;
            const int i1 = min(i0 + 1, TFN - 1);
            const float om = 1.0f - tfr;
            const float4 tlo = tf_s[i0];
            const float4 thi = tf_s[i1];
            const float r = tlo.x * om + thi.x * tfr;
            const float g = tlo.y * om + thi.y * tfr;
            const float b = tlo.z * om + thi.z * tfr;
            const float a = tlo.w * om + thi.w * tfr;

            // SAMPLING_RATE == 1 -> pow(x, 1.0) == x
            const float alpha = 1.0f - fmaxf(1.0f - a, 1e-7f);
            const float w = (1.0f - acc_a) * alpha;
            acc_r += w * r;
            acc_g += w * g;
            acc_b += w * b;
            acc_a += w;

            ++k;
            if (!more || acc_a >= 0.99f) break;
            A = A2; B = B2; C = C2; D = D2;
            fx = fx2; fy = fy2; fz = fz2;
        }
    }

    const int o = (px * RH + py) * 4;
    out[o + 0] = acc_r;
    out[o + 1] = acc_g;
    out[o + 2] = acc_b;
    out[o + 3] = acc_a;
}

extern "C" void kernel_launch(void* const* d_in, const int* in_sizes, int n_in,
                              void* d_out, int out_size, void* d_ws, size_t ws_size,
                              hipStream_t stream) {
    const float* vol = (const float*)d_in[0];
    const float4* tf = (const float4*)d_in[1];
    const float* lf  = (const float*)d_in[2];
    float* out = (float*)d_out;

    dim3 grid(RW / 16, RH / 16);   // 16x16 pixel tiles, 256 threads each
    raycast_kernel<<<grid, 256, 0, stream>>>(vol, tf, lf, out);
}